// Round 4
// baseline (410.699 us; speedup 1.0000x reference)
//
#include <hip/hip_runtime.h>
#include <hip/hip_bf16.h>
#include <stdint.h>

// SpatialMHA: B=64 S=256 E=1024 H=16 D=64
// qkv = x @ Win^T + bin ; attn with additive spatial bias ; out = x + ctx @ Wout^T + bout

typedef __attribute__((ext_vector_type(8))) __bf16 bf16x8;
typedef __attribute__((ext_vector_type(4))) float f32x4;

#define DEVI static __device__ __forceinline__

DEVI unsigned short f2bf(float f) {           // fp32 -> bf16 round-to-nearest-even
  union { float f; unsigned u; } x; x.f = f;
  unsigned r = x.u + 0x7fffu + ((x.u >> 16) & 1u);
  return (unsigned short)(r >> 16);
}

typedef unsigned int __attribute__((address_space(1))) u32_g;
typedef unsigned int __attribute__((address_space(3))) u32_l;

DEVI void g2l16(const unsigned short* g, unsigned short* l) {
  // async global->LDS, 16B per lane; LDS dest = wave-uniform base + lane*16
  __builtin_amdgcn_global_load_lds((const u32_g*)g, (u32_l*)l, 16, 0, 0);
}

// ---------------------------------------------------------------- fp32->bf16
__global__ __launch_bounds__(256) void cvt_kernel(const float* __restrict__ s,
                                                  unsigned short* __restrict__ d, int n) {
  int i = (blockIdx.x * 256 + threadIdx.x) * 4;
  if (i >= n) return;
  float4 v = *(const float4*)(s + i);
  ushort4 o;
  o.x = f2bf(v.x); o.y = f2bf(v.y); o.z = f2bf(v.z); o.w = f2bf(v.w);
  *(ushort4*)(d + i) = o;
}

// ---------------------------------------------------------------- 256x256 GEMM (B^T layout)
// C[m,n] = sum_k A[m,k]*Bw[n,k]; K=1024. 8 waves (2M x 4N), per-wave 128x64 C.
// 32 slabs of BK=32; LDS = 4-slot ring per operand (4x16KB A + 4x16KB B = 128KB).
// Register-double-buffered frags: per phase p
//   STAGE(p+3) -> vmcnt(8) -> s_barrier -> ds_read slab p+1 into NXT (no wait)
//   -> 32 MFMA on CUR (reg-only, overlaps in-flight ds_reads) -> lgkmcnt(0)
//   -> sched_barrier(0) -> swap.
// launch_bounds (512,1): the (512,2) variant capped unified VGPR+AGPR at 256 and
// SPILLED (R2: FETCH +35MB, WRITE +58MB of scratch traffic, MfmaUtil 19%). LDS
// already limits to 1 block/CU, so min-waves=1 costs nothing and lifts the cap.
// Slot-reuse: STAGE(p+3) writes slot (p-1)&3; its readers (LOADF at phase p-2)
// drained lgkmcnt(0) before phase p-1's barrier. XOR swizzle ((row>>1)&3)<<4 keeps
// ds_read_b128 conflict-free (verified 0 conflicts in R1/R2); global source pre-swizzled.
template <int EPI>
__global__ __launch_bounds__(512, 1)
void gemm8(const unsigned short* __restrict__ A,
           const unsigned short* __restrict__ Bw,
           const float* __restrict__ bias,
           unsigned short* __restrict__ Qo,
           unsigned short* __restrict__ Ko,
           unsigned short* __restrict__ VTo,
           const float* __restrict__ Xres,
           float* __restrict__ Out) {
  extern __shared__ unsigned short lds[];   // [0,32768): A ring, [32768,65536): B ring (elems)
  const int lane = threadIdx.x & 63, wid = threadIdx.x >> 6;
  const int l15 = lane & 15, lg = lane >> 4;
  const int wr = wid >> 2, wcn = wid & 3;
  const int am0 = blockIdx.x * 256, bn0 = blockIdx.y * 256;

  const int srow0 = wid * 16 + (lane >> 2);   // staging row (+ j*128)
  const int scb0  = (lane & 3) * 16;          // staging linear col-byte

  f32x4 acc[8][4] = {};
  bf16x8 aA[8], bA[4], aB[8], bB[4];

#define SWZ(row) ((((row) >> 1) & 3) << 4)

#define STAGE(s) { \
    const int slot_ = (s) & 3; \
    _Pragma("unroll") \
    for (int j = 0; j < 2; ++j) { \
      const int row_ = j * 128 + srow0; \
      const int cs_ = scb0 ^ SWZ(row_); \
      g2l16(A  + (size_t)(am0 + row_) * 1024 + (s) * 32 + (cs_ >> 1), \
            &lds[slot_ * 8192 + j * 4096 + wid * 512]); \
      g2l16(Bw + (size_t)(bn0 + row_) * 1024 + (s) * 32 + (cs_ >> 1), \
            &lds[32768 + slot_ * 8192 + j * 4096 + wid * 512]); \
    } }

#define LOADF(AF, BF, p) { \
    const unsigned short* As_ = &lds[((p) & 3) * 8192]; \
    const unsigned short* Bs_ = &lds[32768 + ((p) & 3) * 8192]; \
    _Pragma("unroll") \
    for (int mf = 0; mf < 8; ++mf) { \
      const int row_ = wr * 128 + mf * 16 + l15; \
      AF[mf] = *(const bf16x8*)((const char*)As_ + row_ * 64 + ((lg * 16) ^ SWZ(row_))); \
    } \
    _Pragma("unroll") \
    for (int nf = 0; nf < 4; ++nf) { \
      const int row_ = wcn * 64 + nf * 16 + l15; \
      BF[nf] = *(const bf16x8*)((const char*)Bs_ + row_ * 64 + ((lg * 16) ^ SWZ(row_))); \
    } }

#define MFMAS(AF, BF) { \
    __builtin_amdgcn_s_setprio(1); \
    _Pragma("unroll") \
    for (int mf = 0; mf < 8; ++mf) \
      _Pragma("unroll") \
      for (int nf = 0; nf < 4; ++nf) \
        acc[mf][nf] = __builtin_amdgcn_mfma_f32_16x16x32_bf16(AF[mf], BF[nf], acc[mf][nf], 0, 0, 0); \
    __builtin_amdgcn_s_setprio(0); }

  // PHASE p: consume slab p from (AC,BC); prefetch frags of slab p+1 into (AN,BN).
#define PHASE(p, AC, BC, AN, BN, DOSTAGE, VM) { \
    if (DOSTAGE) STAGE((p) + 3) \
    asm volatile("s_waitcnt vmcnt(" #VM ")" ::: "memory"); \
    __builtin_amdgcn_s_barrier(); \
    LOADF(AN, BN, (p) + 1) \
    MFMAS(AC, BC) \
    asm volatile("s_waitcnt lgkmcnt(0)" ::: "memory"); \
    __builtin_amdgcn_sched_barrier(0); }

  // prologue: stage slabs 0..2, wait slab0, load its frags
  STAGE(0) STAGE(1) STAGE(2)
  asm volatile("s_waitcnt vmcnt(8)" ::: "memory");
  __builtin_amdgcn_s_barrier();
  LOADF(aA, bA, 0)
  asm volatile("s_waitcnt lgkmcnt(0)" ::: "memory");
  __builtin_amdgcn_sched_barrier(0);

#pragma unroll 2
  for (int p = 0; p < 28; p += 2) {
    PHASE(p,     aA, bA, aB, bB, 1, 8)
    PHASE(p + 1, aB, bB, aA, bA, 1, 8)
  }
  PHASE(28, aA, bA, aB, bB, 1, 8)
  PHASE(29, aB, bB, aA, bA, 0, 4)
  PHASE(30, aA, bA, aB, bB, 0, 0)
  MFMAS(aB, bB)   // slab 31

  // C frag mapping: col = bn0 + wcn*64 + nf*16 + l15 ; row = am0 + wr*128 + mf*16 + lg*4 + r
  if (EPI == 0) {
#pragma unroll
    for (int nf = 0; nf < 4; ++nf) {
      const int col = bn0 + wcn * 64 + nf * 16 + l15;   // 0..3071
      const int which = col >> 10;                      // 0=Q 1=K 2=V (uniform per block)
      const int e = col & 1023;
      const int hh = e >> 6, dd = e & 63;
      const float bv = bias[col];
#pragma unroll
      for (int mf = 0; mf < 8; ++mf) {
        const int row0 = am0 + wr * 128 + mf * 16 + lg * 4;  // multiple of 4
        const int bb = row0 >> 8;
        const int s0 = row0 & 255;
        if (which == 2) {
          unsigned long long pk = 0;
#pragma unroll
          for (int r = 0; r < 4; ++r)
            pk |= (unsigned long long)f2bf(acc[mf][nf][r] + bv) << (16 * r);
          *(unsigned long long*)&VTo[((size_t)(bb * 16 + hh) * 64 + dd) * 256 + s0] = pk;
        } else {
          unsigned short* dst = (which == 0) ? Qo : Ko;
#pragma unroll
          for (int r = 0; r < 4; ++r)
            dst[((size_t)(bb * 16 + hh) * 256 + s0 + r) * 64 + dd] = f2bf(acc[mf][nf][r] + bv);
        }
      }
    }
  } else {
#pragma unroll
    for (int nf = 0; nf < 4; ++nf) {
      const int col = bn0 + wcn * 64 + nf * 16 + l15;
      const float bv = bias[col];
#pragma unroll
      for (int mf = 0; mf < 8; ++mf) {
#pragma unroll
        for (int r = 0; r < 4; ++r) {
          const int row = am0 + wr * 128 + mf * 16 + lg * 4 + r;
          const size_t idx = (size_t)row * 1024 + col;
          Out[idx] = Xres[idx] + acc[mf][nf][r] + bv;
        }
      }
    }
  }
#undef SWZ
#undef STAGE
#undef LOADF
#undef MFMAS
#undef PHASE
}

// ---------------------------------------------------------------- fused attention
// One block per (b,h); 4 waves, each owns 64 q rows. FA2 online softmax over 4 key
// chunks of 64. Scores computed transposed: S^T = mfma(A=K, B=Q) -> row=key, col=q,
// so the row-softmax reduces with just shfl_xor 16/32. P staged per-wave in padded
// LDS (stride 160B -> 4-way banks) to transpose for the PV mfma A-operand.
__global__ __launch_bounds__(256) void attn_kernel(const unsigned short* __restrict__ Qg,
                                                   const unsigned short* __restrict__ Kg,
                                                   const unsigned short* __restrict__ VTg,
                                                   const float* __restrict__ bias,
                                                   unsigned short* __restrict__ ctx) {
  __shared__ unsigned short P[4][64][80];   // per-wave private [q][k], pad 64->80
  const int lane = threadIdx.x & 63, wave = threadIdx.x >> 6;
  const int l15 = lane & 15, lg = lane >> 4;
  const int bh = blockIdx.x;
  const int bb = bh >> 4, hh = bh & 15;
  const size_t base = (size_t)bh * (256 * 64);
  const int q0 = wave * 64;

  // Q as B-operand fragments: lane holds Q[q0+qi*16+l15][kc*32+lg*8 .. +8]
  bf16x8 qfr[4][2];
#pragma unroll
  for (int qi = 0; qi < 4; ++qi)
#pragma unroll
    for (int kc = 0; kc < 2; ++kc)
      qfr[qi][kc] = *(const bf16x8*)&Qg[base + (size_t)(q0 + qi * 16 + l15) * 64 + kc * 32 + lg * 8];

  f32x4 o[4][4] = {};
  float mrow[4], lrow[4];
#pragma unroll
  for (int i = 0; i < 4; ++i) { mrow[i] = -1e30f; lrow[i] = 0.f; }

  for (int c = 0; c < 4; ++c) {
    // K as A-operand fragments
    bf16x8 kfr[4][2];
#pragma unroll
    for (int kr = 0; kr < 4; ++kr)
#pragma unroll
      for (int kc = 0; kc < 2; ++kc)
        kfr[kr][kc] = *(const bf16x8*)&Kg[base + (size_t)(c * 64 + kr * 16 + l15) * 64 + kc * 32 + lg * 8];

    // S^T chunk [64k x 64q]
    f32x4 s[4][4] = {};
#pragma unroll
    for (int kr = 0; kr < 4; ++kr)
#pragma unroll
      for (int qi = 0; qi < 4; ++qi)
#pragma unroll
        for (int kc = 0; kc < 2; ++kc)
          s[kr][qi] = __builtin_amdgcn_mfma_f32_16x16x32_bf16(kfr[kr][kc], qfr[qi][kc], s[kr][qi], 0, 0, 0);

    // scale + spatial bias (float4 over r: krow consecutive); chunk max per q-column
    float cmax[4];
#pragma unroll
    for (int qi = 0; qi < 4; ++qi) cmax[qi] = -1e30f;
#pragma unroll
    for (int kr = 0; kr < 4; ++kr)
#pragma unroll
      for (int qi = 0; qi < 4; ++qi) {
        const int krow0 = c * 64 + kr * 16 + lg * 4;
        const int qcol = q0 + qi * 16 + l15;
        const f32x4 b4 = *(const f32x4*)&bias[qcol * 256 + krow0];
#pragma unroll
        for (int r = 0; r < 4; ++r) {
          float v = s[kr][qi][r] * 0.125f + b4[r];
          s[kr][qi][r] = v;
          cmax[qi] = fmaxf(cmax[qi], v);
        }
      }
#pragma unroll
    for (int qi = 0; qi < 4; ++qi) {
      cmax[qi] = fmaxf(cmax[qi], __shfl_xor(cmax[qi], 16, 64));
      cmax[qi] = fmaxf(cmax[qi], __shfl_xor(cmax[qi], 32, 64));
    }
    float resc[4], csum[4];
#pragma unroll
    for (int qi = 0; qi < 4; ++qi) {
      float mn = fmaxf(mrow[qi], cmax[qi]);
      resc[qi] = __expf(mrow[qi] - mn);
      mrow[qi] = mn;
      csum[qi] = 0.f;
    }
#pragma unroll
    for (int kr = 0; kr < 4; ++kr)
#pragma unroll
      for (int qi = 0; qi < 4; ++qi)
#pragma unroll
        for (int r = 0; r < 4; ++r) {
          float e = __expf(s[kr][qi][r] - mrow[qi]);
          s[kr][qi][r] = e;
          csum[qi] += e;
        }
#pragma unroll
    for (int qi = 0; qi < 4; ++qi) {
      csum[qi] += __shfl_xor(csum[qi], 16, 64);
      csum[qi] += __shfl_xor(csum[qi], 32, 64);
      lrow[qi] = lrow[qi] * resc[qi] + csum[qi];
    }

    // P -> LDS transposed to [q][k] (per-wave private; within-wave sync only)
#pragma unroll
    for (int kr = 0; kr < 4; ++kr)
#pragma unroll
      for (int qi = 0; qi < 4; ++qi)
#pragma unroll
        for (int r = 0; r < 4; ++r)
          P[wave][qi * 16 + l15][kr * 16 + lg * 4 + r] = f2bf(s[kr][qi][r]);
    asm volatile("s_waitcnt lgkmcnt(0)" ::: "memory");

    // rescale O: factor for q-row = lg*4+r lives in lane (lg*4+r) of resc[qrf]
#pragma unroll
    for (int qrf = 0; qrf < 4; ++qrf)
#pragma unroll
      for (int r = 0; r < 4; ++r) {
        float f = __shfl(resc[qrf], lg * 4 + r, 64);
#pragma unroll
        for (int df = 0; df < 4; ++df) o[qrf][df][r] *= f;
      }

    // PV: A = P[q][k] from LDS, B = V[k][d] read from V^T (contiguous)
    bf16x8 vb[2][4], pa[4][2];
#pragma unroll
    for (int kc = 0; kc < 2; ++kc)
#pragma unroll
      for (int df = 0; df < 4; ++df)
        vb[kc][df] = *(const bf16x8*)&VTg[base + (size_t)(df * 16 + l15) * 256 + c * 64 + kc * 32 + lg * 8];
#pragma unroll
    for (int qrf = 0; qrf < 4; ++qrf)
#pragma unroll
      for (int kc = 0; kc < 2; ++kc)
        pa[qrf][kc] = *(const bf16x8*)&P[wave][qrf * 16 + l15][kc * 32 + lg * 8];
#pragma unroll
    for (int qrf = 0; qrf < 4; ++qrf)
#pragma unroll
      for (int df = 0; df < 4; ++df)
#pragma unroll
        for (int kc = 0; kc < 2; ++kc)
          o[qrf][df] = __builtin_amdgcn_mfma_f32_16x16x32_bf16(pa[qrf][kc], vb[kc][df], o[qrf][df], 0, 0, 0);
  }

  // normalize and write ctx [B,S,E] bf16
#pragma unroll
  for (int qrf = 0; qrf < 4; ++qrf)
#pragma unroll
    for (int r = 0; r < 4; ++r) {
      float li = __shfl(lrow[qrf], lg * 4 + r, 64);
      float inv = 1.0f / li;
      const int q = q0 + qrf * 16 + lg * 4 + r;
#pragma unroll
      for (int df = 0; df < 4; ++df) {
        const int d = df * 16 + l15;
        ctx[((size_t)(bb * 256 + q) * 16 + hh) * 64 + d] = f2bf(o[qrf][df][r] * inv);
      }
    }
}

// ---------------------------------------------------------------- launch
extern "C" void kernel_launch(void* const* d_in, const int* in_sizes, int n_in,
                              void* d_out, int out_size, void* d_ws, size_t ws_size,
                              hipStream_t stream) {
  const float* x  = (const float*)d_in[0];
  const float* wi = (const float*)d_in[1];
  const float* bi = (const float*)d_in[2];
  const float* wo = (const float*)d_in[3];
  const float* bo = (const float*)d_in[4];
  const float* sb = (const float*)d_in[5];
  float* out = (float*)d_out;

  char* ws = (char*)d_ws;
  // ws layout (bytes): x_bf/ctx 33554432 | w_in 6291456 | w_out 2097152 | Q | K | VT
  unsigned short* xbf  = (unsigned short*)(ws);
  unsigned short* winb = (unsigned short*)(ws + 33554432u);
  unsigned short* wob  = (unsigned short*)(ws + 39845888u);
  unsigned short* Qb   = (unsigned short*)(ws + 41943040u);
  unsigned short* Kb   = (unsigned short*)(ws + 75497472u);
  unsigned short* VTb  = (unsigned short*)(ws + 109051904u);
  unsigned short* ctx  = xbf;   // x_bf dead after QKV GEMM; reuse for ctx

  // 128KB dynamic LDS needs the attribute raised past the 64KB default
  (void)hipFuncSetAttribute(reinterpret_cast<const void*>(gemm8<0>),
                            hipFuncAttributeMaxDynamicSharedMemorySize, 131072);
  (void)hipFuncSetAttribute(reinterpret_cast<const void*>(gemm8<1>),
                            hipFuncAttributeMaxDynamicSharedMemorySize, 131072);

  cvt_kernel<<<16384, 256, 0, stream>>>(x, xbf, 16777216);
  cvt_kernel<<<3072, 256, 0, stream>>>(wi, winb, 3145728);
  cvt_kernel<<<1024, 256, 0, stream>>>(wo, wob, 1048576);

  // QKV: M=16384 N=3072 K=1024
  gemm8<0><<<dim3(64, 12), 512, 131072, stream>>>(xbf, winb, bi, Qb, Kb, VTb, nullptr, nullptr);

  // attention: one block per (b,h)
  attn_kernel<<<1024, 256, 0, stream>>>(Qb, Kb, VTb, sb, ctx);

  // out-proj + residual: M=16384 N=1024 K=1024
  gemm8<1><<<dim3(64, 4), 512, 131072, stream>>>(ctx, wob, bo, nullptr, nullptr, nullptr, x, out);
}

// Round 5
// 300.691 us; speedup vs baseline: 1.3659x; 1.3659x over previous
//
#include <hip/hip_runtime.h>
#include <hip/hip_bf16.h>
#include <stdint.h>

// SpatialMHA: B=64 S=256 E=1024 H=16 D=64
// qkv = x @ Win^T + bin ; attn with additive spatial bias ; out = x + ctx @ Wout^T + bout

typedef __attribute__((ext_vector_type(8))) __bf16 bf16x8;
typedef __attribute__((ext_vector_type(4))) float f32x4;

#define DEVI static __device__ __forceinline__

DEVI unsigned short f2bf(float f) {           // fp32 -> bf16 round-to-nearest-even
  union { float f; unsigned u; } x; x.f = f;
  unsigned r = x.u + 0x7fffu + ((x.u >> 16) & 1u);
  return (unsigned short)(r >> 16);
}

typedef unsigned int __attribute__((address_space(1))) u32_g;
typedef unsigned int __attribute__((address_space(3))) u32_l;

DEVI void g2l16(const unsigned short* g, unsigned short* l) {
  // async global->LDS, 16B per lane; LDS dest = wave-uniform base + lane*16
  __builtin_amdgcn_global_load_lds((const u32_g*)g, (u32_l*)l, 16, 0, 0);
}

// ---------------------------------------------------------------- fp32->bf16
__global__ __launch_bounds__(256) void cvt_kernel(const float* __restrict__ s,
                                                  unsigned short* __restrict__ d, int n) {
  int i = (blockIdx.x * 256 + threadIdx.x) * 4;
  if (i >= n) return;
  float4 v = *(const float4*)(s + i);
  ushort4 o;
  o.x = f2bf(v.x); o.y = f2bf(v.y); o.z = f2bf(v.z); o.w = f2bf(v.w);
  *(ushort4*)(d + i) = o;
}

// ---------------------------------------------------------------- 256x256 GEMM, 8-phase
// C[m,n] = sum_k A[m,k]*Bw[n,k]; K=1024 = 16 K-tiles of BK=64. 8 waves (2M x 4N),
// per-wave 128x64 C (acc 8x4 f32x4 = 128 AGPR). LDS: 2 K-tile double buffer,
// buf = kt&1, each 64KB (A 256x64 + B 256x64). m201-style schedule: per K-tile
// 4 quadrant phases {Q1=aLo*bLo, Q2=aLo*bHi, Q3=aHi*bHi, Q4=aHi*bLo}; each phase:
//   [ds_read new quadrant frags] [stage one half-tile, 2x gload_lds]
//   [p4/p8 only: vmcnt(2)] barrier; lgkmcnt(0); setprio(1) 16 MFMA setprio(0)
// Peak live frags a[4][2]+b0[2][2]+b1[2][2] = 64 VGPR -> ~230 total, fits the
// 256-reg cap that an 8-wave block forces (R2/R3 full dbuf = 264 -> spilled).
// Stage plan (iter i, kts 2i,2i+1 computed): p1:kt(2i+1).Bhi p2:kt(2i+1).Alo
// p3:kt(2i+1).Ahi p4:kt(2i+2).Blo p5:kt(2i+2).Bhi p6:kt(2i+2).Alo p7:kt(2i+2).Ahi
// p8:kt(2i+3).Blo.  Safety: A-halves last read p3 -> staged >=p5 (2-barrier lag);
// B-halves last read p2 -> staged >=p4. Availability: kt2i complete at i-1:p7,
// p8's vmcnt(2) leaves only p8's stage -> landed before p1 reads. Swizzle for
// 128B rows: 16B-granule ^= (row&7) on both stage source and ds_read -> uniform
// 8 lanes/granule (the b128 floor).
template <int EPI>
__global__ __launch_bounds__(512, 2)
void gemm256(const unsigned short* __restrict__ A,
             const unsigned short* __restrict__ Bw,
             const float* __restrict__ bias,
             unsigned short* __restrict__ Qo,
             unsigned short* __restrict__ Ko,
             unsigned short* __restrict__ VTo,
             const float* __restrict__ Xres,
             float* __restrict__ Out) {
  extern __shared__ unsigned short lds[];   // 65536 elems = 128KB
  const int lane = threadIdx.x & 63, wid = threadIdx.x >> 6;
  const int l15 = lane & 15, lg = lane >> 4;
  const int wr = wid >> 2, wcn = wid & 3;
  const int am0 = blockIdx.x * 256, bn0 = blockIdx.y * 256;

  f32x4 acc[8][4] = {};
  bf16x8 a[4][2], b0[2][2], b1[2][2];

#define VMC(N) asm volatile("s_waitcnt vmcnt(" #N ")" ::: "memory")
#define LGKM() asm volatile("s_waitcnt lgkmcnt(0)" ::: "memory")
#define BARR() __builtin_amdgcn_s_barrier()

  // stage one half-tile (128 rows x 64 cols) of operand OP (0=A,1=B) of K-tile KT
#define STAGEH(OP, KT, HALF) { \
    const int buf_ = (KT) & 1; \
    _Pragma("unroll") \
    for (int c = 0; c < 2; ++c) { \
      const int rloc_ = (HALF) * 128 + c * 64 + wid * 8 + (lane >> 3); \
      const int ge_ = (KT) * 64 + (((lane & 7) ^ (rloc_ & 7)) << 3); \
      const unsigned short* src_ = (OP) ? Bw + (size_t)(bn0 + rloc_) * 1024 + ge_ \
                                        : A  + (size_t)(am0 + rloc_) * 1024 + ge_; \
      g2l16(src_, &lds[buf_ * 32768 + (OP) * 16384 + ((HALF) * 128 + c * 64 + wid * 8) * 64]); \
    } }

#define RDA(DST, KT, HALF) { \
    const unsigned short* base_ = &lds[((KT) & 1) * 32768]; \
    _Pragma("unroll") \
    for (int mfi = 0; mfi < 4; ++mfi) { \
      const int row_ = wr * 128 + (HALF) * 64 + mfi * 16 + l15; \
      _Pragma("unroll") \
      for (int kk = 0; kk < 2; ++kk) \
        DST[mfi][kk] = *(const bf16x8*)((const char*)base_ + row_ * 128 + ((kk * 64 + lg * 16) ^ ((row_ & 7) << 4))); \
    } }

#define RDB(DST, KT, HALF) { \
    const unsigned short* base_ = &lds[((KT) & 1) * 32768 + 16384]; \
    _Pragma("unroll") \
    for (int nfi = 0; nfi < 2; ++nfi) { \
      const int row_ = wcn * 64 + (HALF) * 32 + nfi * 16 + l15; \
      _Pragma("unroll") \
      for (int kk = 0; kk < 2; ++kk) \
        DST[nfi][kk] = *(const bf16x8*)((const char*)base_ + row_ * 128 + ((kk * 64 + lg * 16) ^ ((row_ & 7) << 4))); \
    } }

#define MM(AF, BF, HA, HB) { \
    __builtin_amdgcn_s_setprio(1); \
    _Pragma("unroll") \
    for (int mfi = 0; mfi < 4; ++mfi) \
      _Pragma("unroll") \
      for (int nfi = 0; nfi < 2; ++nfi) \
        _Pragma("unroll") \
        for (int kk = 0; kk < 2; ++kk) \
          acc[(HA) * 4 + mfi][(HB) * 2 + nfi] = __builtin_amdgcn_mfma_f32_16x16x32_bf16( \
              AF[mfi][kk], BF[nfi][kk], acc[(HA) * 4 + mfi][(HB) * 2 + nfi], 0, 0, 0); \
    __builtin_amdgcn_s_setprio(0); }

  // prologue: kt0 fully + kt1.Blo; kt0 landed (vmcnt(2) leaves kt1.Blo in flight)
  STAGEH(0, 0, 0) STAGEH(0, 0, 1) STAGEH(1, 0, 0) STAGEH(1, 0, 1) STAGEH(1, 1, 0)
  VMC(2); BARR();

#pragma unroll 1
  for (int i = 0; i < 7; ++i) {
    const int k0 = 2 * i, k1 = 2 * i + 1;
    RDA(a, k0, 0) RDB(b0, k0, 0) STAGEH(1, k1, 1)     BARR(); LGKM(); MM(a, b0, 0, 0)  // p1
    RDB(b1, k0, 1)               STAGEH(0, k1, 0)     BARR(); LGKM(); MM(a, b1, 0, 1)  // p2
    RDA(a, k0, 1)                STAGEH(0, k1, 1)     BARR(); LGKM(); MM(a, b1, 1, 1)  // p3
                                 STAGEH(1, k1 + 1, 0) VMC(2); BARR(); MM(a, b0, 1, 0)  // p4
    RDA(a, k1, 0) RDB(b0, k1, 0) STAGEH(1, k1 + 1, 1) BARR(); LGKM(); MM(a, b0, 0, 0)  // p5
    RDB(b1, k1, 1)               STAGEH(0, k1 + 1, 0) BARR(); LGKM(); MM(a, b1, 0, 1)  // p6
    RDA(a, k1, 1)                STAGEH(0, k1 + 1, 1) BARR(); LGKM(); MM(a, b1, 1, 1)  // p7
                                 STAGEH(1, k1 + 2, 0) VMC(2); BARR(); MM(a, b0, 1, 0)  // p8
  }
  // iter 7: kts 14,15; stages for kt16+ dropped, drain at p4
  RDA(a, 14, 0) RDB(b0, 14, 0) STAGEH(1, 15, 1) BARR(); LGKM(); MM(a, b0, 0, 0)
  RDB(b1, 14, 1)               STAGEH(0, 15, 0) BARR(); LGKM(); MM(a, b1, 0, 1)
  RDA(a, 14, 1)                STAGEH(0, 15, 1) BARR(); LGKM(); MM(a, b1, 1, 1)
                                                VMC(0); BARR(); MM(a, b0, 1, 0)
  RDA(a, 15, 0) RDB(b0, 15, 0)                  BARR(); LGKM(); MM(a, b0, 0, 0)
  RDB(b1, 15, 1)                                BARR(); LGKM(); MM(a, b1, 0, 1)
  RDA(a, 15, 1)                                 BARR(); LGKM(); MM(a, b1, 1, 1)
                                                                MM(a, b0, 1, 0)

  // C frag mapping: col = bn0 + wcn*64 + nf*16 + l15 ; row = am0 + wr*128 + mf*16 + lg*4 + r
  if (EPI == 0) {
#pragma unroll
    for (int nf = 0; nf < 4; ++nf) {
      const int col = bn0 + wcn * 64 + nf * 16 + l15;   // 0..3071
      const int which = col >> 10;                      // 0=Q 1=K 2=V (uniform per block)
      const int e = col & 1023;
      const int hh = e >> 6, dd = e & 63;
      const float bv = bias[col];
#pragma unroll
      for (int mf = 0; mf < 8; ++mf) {
        const int row0 = am0 + wr * 128 + mf * 16 + lg * 4;  // multiple of 4
        const int bb = row0 >> 8;
        const int s0 = row0 & 255;
        if (which == 2) {
          unsigned long long pk = 0;
#pragma unroll
          for (int r = 0; r < 4; ++r)
            pk |= (unsigned long long)f2bf(acc[mf][nf][r] + bv) << (16 * r);
          *(unsigned long long*)&VTo[((size_t)(bb * 16 + hh) * 64 + dd) * 256 + s0] = pk;
        } else {
          unsigned short* dst = (which == 0) ? Qo : Ko;
#pragma unroll
          for (int r = 0; r < 4; ++r)
            dst[((size_t)(bb * 16 + hh) * 256 + s0 + r) * 64 + dd] = f2bf(acc[mf][nf][r] + bv);
        }
      }
    }
  } else {
#pragma unroll
    for (int nf = 0; nf < 4; ++nf) {
      const int col = bn0 + wcn * 64 + nf * 16 + l15;
      const float bv = bias[col];
#pragma unroll
      for (int mf = 0; mf < 8; ++mf) {
#pragma unroll
        for (int r = 0; r < 4; ++r) {
          const int row = am0 + wr * 128 + mf * 16 + lg * 4 + r;
          const size_t idx = (size_t)row * 1024 + col;
          Out[idx] = Xres[idx] + acc[mf][nf][r] + bv;
        }
      }
    }
  }
#undef VMC
#undef LGKM
#undef BARR
#undef STAGEH
#undef RDA
#undef RDB
#undef MM
}

// ---------------------------------------------------------------- fused attention
// One block per (b,h); 4 waves, each owns 64 q rows. FA2 online softmax over 4 key
// chunks of 64. Scores computed transposed: S^T = mfma(A=K, B=Q) -> row=key, col=q,
// so the row-softmax reduces with just shfl_xor 16/32. P staged per-wave in padded
// LDS (stride 160B -> 4-way banks) to transpose for the PV mfma A-operand.
__global__ __launch_bounds__(256) void attn_kernel(const unsigned short* __restrict__ Qg,
                                                   const unsigned short* __restrict__ Kg,
                                                   const unsigned short* __restrict__ VTg,
                                                   const float* __restrict__ bias,
                                                   unsigned short* __restrict__ ctx) {
  __shared__ unsigned short P[4][64][80];   // per-wave private [q][k], pad 64->80
  const int lane = threadIdx.x & 63, wave = threadIdx.x >> 6;
  const int l15 = lane & 15, lg = lane >> 4;
  const int bh = blockIdx.x;
  const int bb = bh >> 4, hh = bh & 15;
  const size_t base = (size_t)bh * (256 * 64);
  const int q0 = wave * 64;

  // Q as B-operand fragments: lane holds Q[q0+qi*16+l15][kc*32+lg*8 .. +8]
  bf16x8 qfr[4][2];
#pragma unroll
  for (int qi = 0; qi < 4; ++qi)
#pragma unroll
    for (int kc = 0; kc < 2; ++kc)
      qfr[qi][kc] = *(const bf16x8*)&Qg[base + (size_t)(q0 + qi * 16 + l15) * 64 + kc * 32 + lg * 8];

  f32x4 o[4][4] = {};
  float mrow[4], lrow[4];
#pragma unroll
  for (int i = 0; i < 4; ++i) { mrow[i] = -1e30f; lrow[i] = 0.f; }

  for (int c = 0; c < 4; ++c) {
    // K as A-operand fragments
    bf16x8 kfr[4][2];
#pragma unroll
    for (int kr = 0; kr < 4; ++kr)
#pragma unroll
      for (int kc = 0; kc < 2; ++kc)
        kfr[kr][kc] = *(const bf16x8*)&Kg[base + (size_t)(c * 64 + kr * 16 + l15) * 64 + kc * 32 + lg * 8];

    // S^T chunk [64k x 64q]
    f32x4 s[4][4] = {};
#pragma unroll
    for (int kr = 0; kr < 4; ++kr)
#pragma unroll
      for (int qi = 0; qi < 4; ++qi)
#pragma unroll
        for (int kc = 0; kc < 2; ++kc)
          s[kr][qi] = __builtin_amdgcn_mfma_f32_16x16x32_bf16(kfr[kr][kc], qfr[qi][kc], s[kr][qi], 0, 0, 0);

    // scale + spatial bias (float4 over r: krow consecutive); chunk max per q-column
    float cmax[4];
#pragma unroll
    for (int qi = 0; qi < 4; ++qi) cmax[qi] = -1e30f;
#pragma unroll
    for (int kr = 0; kr < 4; ++kr)
#pragma unroll
      for (int qi = 0; qi < 4; ++qi) {
        const int krow0 = c * 64 + kr * 16 + lg * 4;
        const int qcol = q0 + qi * 16 + l15;
        const f32x4 b4 = *(const f32x4*)&bias[qcol * 256 + krow0];
#pragma unroll
        for (int r = 0; r < 4; ++r) {
          float v = s[kr][qi][r] * 0.125f + b4[r];
          s[kr][qi][r] = v;
          cmax[qi] = fmaxf(cmax[qi], v);
        }
      }
#pragma unroll
    for (int qi = 0; qi < 4; ++qi) {
      cmax[qi] = fmaxf(cmax[qi], __shfl_xor(cmax[qi], 16, 64));
      cmax[qi] = fmaxf(cmax[qi], __shfl_xor(cmax[qi], 32, 64));
    }
    float resc[4], csum[4];
#pragma unroll
    for (int qi = 0; qi < 4; ++qi) {
      float mn = fmaxf(mrow[qi], cmax[qi]);
      resc[qi] = __expf(mrow[qi] - mn);
      mrow[qi] = mn;
      csum[qi] = 0.f;
    }
#pragma unroll
    for (int kr = 0; kr < 4; ++kr)
#pragma unroll
      for (int qi = 0; qi < 4; ++qi)
#pragma unroll
        for (int r = 0; r < 4; ++r) {
          float e = __expf(s[kr][qi][r] - mrow[qi]);
          s[kr][qi][r] = e;
          csum[qi] += e;
        }
#pragma unroll
    for (int qi = 0; qi < 4; ++qi) {
      csum[qi] += __shfl_xor(csum[qi], 16, 64);
      csum[qi] += __shfl_xor(csum[qi], 32, 64);
      lrow[qi] = lrow[qi] * resc[qi] + csum[qi];
    }

    // P -> LDS transposed to [q][k] (per-wave private; within-wave sync only)
#pragma unroll
    for (int kr = 0; kr < 4; ++kr)
#pragma unroll
      for (int qi = 0; qi < 4; ++qi)
#pragma unroll
        for (int r = 0; r < 4; ++r)
          P[wave][qi * 16 + l15][kr * 16 + lg * 4 + r] = f2bf(s[kr][qi][r]);
    asm volatile("s_waitcnt lgkmcnt(0)" ::: "memory");

    // rescale O: factor for q-row = lg*4+r lives in lane (lg*4+r) of resc[qrf]
#pragma unroll
    for (int qrf = 0; qrf < 4; ++qrf)
#pragma unroll
      for (int r = 0; r < 4; ++r) {
        float f = __shfl(resc[qrf], lg * 4 + r, 64);
#pragma unroll
        for (int df = 0; df < 4; ++df) o[qrf][df][r] *= f;
      }

    // PV: A = P[q][k] from LDS, B = V[k][d] read from V^T (contiguous)
    bf16x8 vb[2][4], pa[4][2];
#pragma unroll
    for (int kc = 0; kc < 2; ++kc)
#pragma unroll
      for (int df = 0; df < 4; ++df)
        vb[kc][df] = *(const bf16x8*)&VTg[base + (size_t)(df * 16 + l15) * 256 + c * 64 + kc * 32 + lg * 8];
#pragma unroll
    for (int qrf = 0; qrf < 4; ++qrf)
#pragma unroll
      for (int kc = 0; kc < 2; ++kc)
        pa[qrf][kc] = *(const bf16x8*)&P[wave][qrf * 16 + l15][kc * 32 + lg * 8];
#pragma unroll
    for (int qrf = 0; qrf < 4; ++qrf)
#pragma unroll
      for (int df = 0; df < 4; ++df)
#pragma unroll
        for (int kc = 0; kc < 2; ++kc)
          o[qrf][df] = __builtin_amdgcn_mfma_f32_16x16x32_bf16(pa[qrf][kc], vb[kc][df], o[qrf][df], 0, 0, 0);
  }

  // normalize and write ctx [B,S,E] bf16
#pragma unroll
  for (int qrf = 0; qrf < 4; ++qrf)
#pragma unroll
    for (int r = 0; r < 4; ++r) {
      float li = __shfl(lrow[qrf], lg * 4 + r, 64);
      float inv = 1.0f / li;
      const int q = q0 + qrf * 16 + lg * 4 + r;
#pragma unroll
      for (int df = 0; df < 4; ++df) {
        const int d = df * 16 + l15;
        ctx[((size_t)(bb * 256 + q) * 16 + hh) * 64 + d] = f2bf(o[qrf][df][r] * inv);
      }
    }
}

// ---------------------------------------------------------------- launch
extern "C" void kernel_launch(void* const* d_in, const int* in_sizes, int n_in,
                              void* d_out, int out_size, void* d_ws, size_t ws_size,
                              hipStream_t stream) {
  const float* x  = (const float*)d_in[0];
  const float* wi = (const float*)d_in[1];
  const float* bi = (const float*)d_in[2];
  const float* wo = (const float*)d_in[3];
  const float* bo = (const float*)d_in[4];
  const float* sb = (const float*)d_in[5];
  float* out = (float*)d_out;

  char* ws = (char*)d_ws;
  // ws layout (bytes): x_bf/ctx 33554432 | w_in 6291456 | w_out 2097152 | Q | K | VT
  unsigned short* xbf  = (unsigned short*)(ws);
  unsigned short* winb = (unsigned short*)(ws + 33554432u);
  unsigned short* wob  = (unsigned short*)(ws + 39845888u);
  unsigned short* Qb   = (unsigned short*)(ws + 41943040u);
  unsigned short* Kb   = (unsigned short*)(ws + 75497472u);
  unsigned short* VTb  = (unsigned short*)(ws + 109051904u);
  unsigned short* ctx  = xbf;   // x_bf dead after QKV GEMM; reuse for ctx

  // 128KB dynamic LDS needs the attribute raised past the 64KB default
  (void)hipFuncSetAttribute(reinterpret_cast<const void*>(gemm256<0>),
                            hipFuncAttributeMaxDynamicSharedMemorySize, 131072);
  (void)hipFuncSetAttribute(reinterpret_cast<const void*>(gemm256<1>),
                            hipFuncAttributeMaxDynamicSharedMemorySize, 131072);

  cvt_kernel<<<16384, 256, 0, stream>>>(x, xbf, 16777216);
  cvt_kernel<<<3072, 256, 0, stream>>>(wi, winb, 3145728);
  cvt_kernel<<<1024, 256, 0, stream>>>(wo, wob, 1048576);

  // QKV: M=16384 N=3072 K=1024
  gemm256<0><<<dim3(64, 12), 512, 131072, stream>>>(xbf, winb, bi, Qb, Kb, VTb, nullptr, nullptr);

  // attention: one block per (b,h)
  attn_kernel<<<1024, 256, 0, stream>>>(Qb, Kb, VTb, sb, ctx);

  // out-proj + residual: M=16384 N=1024 K=1024
  gemm256<1><<<dim3(64, 4), 512, 131072, stream>>>(ctx, wob, bo, nullptr, nullptr, nullptr, x, out);
}